// Round 6
// baseline (662.342 us; speedup 1.0000x reference)
//
#include <hip/hip_runtime.h>

#define B_ 128
#define T_ 1024
#define I_ 128
#define H_ 256
#define O_ 64

// Force a float4's components to stay in VGPRs (phase A only).
#define PIN4(v) asm volatile("" : "+v"((v).x), "+v"((v).y), "+v"((v).z), "+v"((v).w))

__device__ __forceinline__ float fma4(float4 w, float4 h, float a) {
    a = fmaf(w.x, h.x, a); a = fmaf(w.y, h.y, a);
    a = fmaf(w.z, h.z, a); a = fmaf(w.w, h.w, a);
    return a;
}

// ---------------------------------------------------------------------------
// Phase A: xw[t,b,j] = sum_i x[b,t,i]*W_xh[j,i] + b_h[j]
// Same compute as before; the STORE is now [T,B,H]-transposed so the scan
// reads one contiguous 16 KB block per (t, rowgroup) instead of 16 lines
// strided by 1 MB.
// ---------------------------------------------------------------------------
__global__ __launch_bounds__(256, 2)
void xw_gemm_kernel(const float* __restrict__ x, const float* __restrict__ W_xh,
                    const float* __restrict__ b_h, float* __restrict__ xw)
{
    const int tid = threadIdx.x;
    const int jb  = tid & 31;
    const int kb  = tid >> 5;                       // 0..7
    __shared__ __align__(16) float xs[2][8 * I_];   // 2 x 4 KB
    __shared__ __align__(16) float part[64 * 264];  // 66 KB, 8 rows x 8 kg

    float4 w[8][4];                                 // W_xh[jb*8+a][kb*16+c]
#pragma unroll
    for (int a = 0; a < 8; ++a) {
        const float* wr = W_xh + (size_t)(jb * 8 + a) * I_ + kb * 16;
#pragma unroll
        for (int c4 = 0; c4 < 4; ++c4) {
            w[a][c4] = reinterpret_cast<const float4*>(wr)[c4];
            PIN4(w[a][c4]);
        }
    }
    const float bh = b_h[tid];

    const int base = blockIdx.x * 256;              // 256 rows of [B*T] per WG
    const int bidx = base >> 10;                    // batch row (T_=1024)
    const int tbas = base & 1023;                   // t offset base
    {
        const float4* xp = reinterpret_cast<const float4*>(x + (size_t)base * I_);
        reinterpret_cast<float4*>(xs[0])[tid] = xp[tid];
    }
    __syncthreads();

    int buf = 0;
    for (int tile = 0; tile < 32; ++tile) {
        float4 pre = make_float4(0.f, 0.f, 0.f, 0.f);
        if (tile + 1 < 32) {
            const float4* xp = reinterpret_cast<const float4*>(
                x + (size_t)(base + (tile + 1) * 8) * I_);
            pre = xp[tid];
        }

        float4* p4 = reinterpret_cast<float4*>(part);
#pragma unroll 1
        for (int r = 0; r < 8; ++r) {
            const float4* xr = reinterpret_cast<const float4*>(
                xs[buf] + r * I_ + kb * 16);        // broadcast reads
            float acc[8];
#pragma unroll
            for (int a = 0; a < 8; ++a) acc[a] = 0.f;
#pragma unroll
            for (int c4 = 0; c4 < 4; ++c4) {
                const float4 xv = xr[c4];
#pragma unroll
                for (int a = 0; a < 8; ++a) acc[a] = fma4(w[a][c4], xv, acc[a]);
            }
            const int rowb = (kb * 8 + r) * 66;
            p4[rowb + ((jb * 2 + 0) ^ kb)] = make_float4(acc[0], acc[1], acc[2], acc[3]);
            p4[rowb + ((jb * 2 + 1) ^ kb)] = make_float4(acc[4], acc[5], acc[6], acc[7]);
        }
        __syncthreads();

        {   // phase2: lane j=tid reduces 8 rows x 8 groups; store [T,B,H]
            const int q = tid >> 2, m = tid & 3;
            float* orow = xw + ((size_t)(tbas + tile * 8) * B_ + bidx) * H_ + tid;
#pragma unroll
            for (int r = 0; r < 8; ++r) {
                float s = 0.f;
#pragma unroll
                for (int g = 0; g < 8; ++g)
                    s += part[(g * 8 + r) * 264 + (((q ^ g) << 2) | m)];
                orow[(size_t)r * B_ * H_] = s + bh;
            }
        }
        if (tile + 1 < 32)
            reinterpret_cast<float4*>(xs[buf ^ 1])[tid] = pre;
        __syncthreads();
        buf ^= 1;
    }
}

// ---------------------------------------------------------------------------
// Phase B: MFMA scan, 4 waves x 64 rows. Round-5 post-mortem: the 8-wave
// version was LDS-BW-bound (each wave re-reads full h every step: 128 KB/step
// ~ 1540 cyc floor) and used only 64 CUs. Fixes:
//  - 4 waves (256 thr): wave w owns h-rows [w*64,+64) = 4 row-tiles of
//    A-frags, AND out-rows [w*16,+16) over the FULL K -> out stored directly,
//    no opart exchange. B-frag LDS traffic halves to 64 KB/step.
//  - split accumulator chains (accA depth 8, accB depth 16 per row-tile;
//    10 independent chains) so dependent-MFMA latency pipelines.
//  - grid 256 = 32 chunks x 8 rowgroups, 224 steps each (192 warmup + 32 out;
//    chunks c<=6 are exact). All 256 CUs busy.
//  - xw is [T,B,H]: one contiguous 16 KB block per (t, rowgroup).
// Registers: 320 frag floats/lane -> __launch_bounds__(256,1) (512-reg tier);
// MFMA reads A-frags from AGPRs natively (the round-2..4 allocator fight is
// moot by design).
// ---------------------------------------------------------------------------
typedef short bf16x8 __attribute__((ext_vector_type(8)));
typedef float f32x4  __attribute__((ext_vector_type(4)));
#define MFMA16(A, Bv, Cv) __builtin_amdgcn_mfma_f32_16x16x32_bf16(A, Bv, Cv, 0, 0, 0)

__device__ __forceinline__ unsigned f2bf_bits(float f) {   // RNE f32->bf16 bits
    unsigned u = __float_as_uint(f);
    return (u + 0x7FFFu + ((u >> 16) & 1u)) >> 16;
}

// Pack 4 fp32 (consecutive k) into bf16 hi+lo planes and store (swizzled).
__device__ __forceinline__ void h_write(unsigned* hibase, unsigned* lobase,
                                        int n, int qg, int s,
                                        float v0, float v1, float v2, float v3)
{
    unsigned phA, phB, plA, plB;
    asm("v_cvt_pk_bf16_f32 %0, %1, %2" : "=v"(phA) : "v"(v0), "v"(v1));
    asm("v_cvt_pk_bf16_f32 %0, %1, %2" : "=v"(phB) : "v"(v2), "v"(v3));
    float r0 = v0 - __uint_as_float(phA << 16);
    float r1 = v1 - __uint_as_float(phA & 0xFFFF0000u);
    float r2 = v2 - __uint_as_float(phB << 16);
    float r3 = v3 - __uint_as_float(phB & 0xFFFF0000u);
    asm("v_cvt_pk_bf16_f32 %0, %1, %2" : "=v"(plA) : "v"(r0), "v"(r1));
    asm("v_cvt_pk_bf16_f32 %0, %1, %2" : "=v"(plB) : "v"(r2), "v"(r3));
    const int idx = n * 128 + ((s ^ (n & 7)) << 2) + (qg & 1) * 2;
    *reinterpret_cast<uint2*>(hibase + idx) = make_uint2(phA, phB);
    *reinterpret_cast<uint2*>(lobase + idx) = make_uint2(plA, plB);
}

__global__ __launch_bounds__(256, 1)
void rnn_scan_kernel(const float* __restrict__ xw, const float* __restrict__ W_hh,
                     const float* __restrict__ W_out, const float* __restrict__ b_out,
                     float* __restrict__ out)
{
    const int tid  = threadIdx.x;
    const int n    = tid & 15;            // batch col within WG
    const int qg   = (tid >> 4) & 3;      // quad group within wave
    const int w    = tid >> 6;            // wave 0..3
    const int wrow = w * 64;              // h-output row base (4 row-tiles)

    const int rg = blockIdx.x & 7;        // row group (16 batch rows)
    const int c  = blockIdx.x >> 3;       // time chunk 0..31
    const int r0 = rg * 16;

    const int out_lo = c * 32;            // output window [out_lo, out_lo+32)
    const int t_end  = out_lo + 32;
    const int t0     = (out_lo > 192) ? (out_lo - 192) : 0;   // c<=6 exact

    __shared__ unsigned hsb[2][2][2048];  // [buf][hi/lo][16 cols x 128 uint] 32 KB

    // ---- W_hh A-fragments (split bf16 hi+lo) ----
    bf16x8 wa_hi[4][8], wa_lo[4][8];
#pragma unroll
    for (int rt = 0; rt < 4; ++rt)
#pragma unroll
        for (int kt = 0; kt < 8; ++kt) {
            const float* wp = W_hh + (size_t)(wrow + rt * 16 + n) * H_ + kt * 32 + qg * 8;
            bf16x8 hi8, lo8;
#pragma unroll
            for (int j = 0; j < 8; ++j) {
                float f = wp[j];
                unsigned hb = f2bf_bits(f);
                hi8[j] = (short)hb;
                lo8[j] = (short)f2bf_bits(f - __uint_as_float(hb << 16));
            }
            wa_hi[rt][kt] = hi8; wa_lo[rt][kt] = lo8;
        }

    // ---- W_out fragments: wave w owns out-rows [w*16,+16), full K ----
    bf16x8 wo_hi[8], wo_lo[8];
#pragma unroll
    for (int kt = 0; kt < 8; ++kt) {
        const float* op = W_out + (size_t)(w * 16 + n) * H_ + kt * 32 + qg * 8;
        bf16x8 hi8, lo8;
#pragma unroll
        for (int j = 0; j < 8; ++j) {
            float f = op[j];
            unsigned hb = f2bf_bits(f);
            hi8[j] = (short)hb;
            lo8[j] = (short)f2bf_bits(f - __uint_as_float(hb << 16));
        }
        wo_hi[kt] = hi8; wo_lo[kt] = lo8;
    }
    const float4 bo4 = *reinterpret_cast<const float4*>(b_out + w * 16 + qg * 4);

    float* outp = out + ((size_t)(r0 + n) * T_) * O_ + w * 16 + qg * 4;

    // ---- prologue: h_{t0} = relu(xw[t0]) into buf 0; prime xw[t0+1] ----
    {
        const float* xp = xw + ((size_t)t0 * B_ + (r0 + n)) * H_;
#pragma unroll
        for (int rt = 0; rt < 4; ++rt) {
            float4 a = *reinterpret_cast<const float4*>(xp + wrow + rt * 16 + qg * 4);
            h_write(hsb[0][0], hsb[0][1], n, qg, (wrow + rt * 16 + qg * 4) >> 3,
                    fmaxf(a.x, 0.f), fmaxf(a.y, 0.f), fmaxf(a.z, 0.f), fmaxf(a.w, 0.f));
        }
    }
    float4 cur[4];
    {
        const float* xp = xw + ((size_t)(t0 + 1) * B_ + (r0 + n)) * H_;
#pragma unroll
        for (int rt = 0; rt < 4; ++rt)
            cur[rt] = *reinterpret_cast<const float4*>(xp + wrow + rt * 16 + qg * 4);
    }
    __syncthreads();

    int buf = 0;
    const f32x4 z4 = {0.f, 0.f, 0.f, 0.f};

#pragma unroll 1
    for (int t = t0 + 1; t < t_end; ++t) {
        // prefetch xw[t+1] (longest latency first)
        const int tt = (t + 1 < T_) ? (t + 1) : (T_ - 1);
        const float* xp = xw + ((size_t)tt * B_ + (r0 + n)) * H_;
        float4 nx[4];
#pragma unroll
        for (int rt = 0; rt < 4; ++rt)
            nx[rt] = *reinterpret_cast<const float4*>(xp + wrow + rt * 16 + qg * 4);

        const bool douto = (t > out_lo);
        const unsigned* hbR = hsb[buf][0];
        const unsigned* lbR = hsb[buf][1];

        f32x4 accA[4], accB[4];
#pragma unroll
        for (int rt = 0; rt < 4; ++rt) { accA[rt] = z4; accB[rt] = z4; }
        f32x4 oaA = z4, oaB = z4;

#pragma unroll
        for (int kt = 0; kt < 8; ++kt) {
            const int sw = (((kt * 4 + qg) ^ (n & 7)) << 2);
            bf16x8 bhi = *reinterpret_cast<const bf16x8*>(hbR + n * 128 + sw);
            bf16x8 blo = *reinterpret_cast<const bf16x8*>(lbR + n * 128 + sw);
#pragma unroll
            for (int rt = 0; rt < 4; ++rt) {
                accA[rt] = MFMA16(wa_hi[rt][kt], bhi, accA[rt]);
                accB[rt] = MFMA16(wa_lo[rt][kt], bhi, accB[rt]);
                accB[rt] = MFMA16(wa_hi[rt][kt], blo, accB[rt]);
            }
            if (douto) {
                oaA = MFMA16(wo_hi[kt], bhi, oaA);
                oaB = MFMA16(wo_lo[kt], bhi, oaB);
                oaB = MFMA16(wo_hi[kt], blo, oaB);
            }
        }

        // h_t = relu(acc + xw_t) -> other buffer
        {
            unsigned* hbW = hsb[buf ^ 1][0];
            unsigned* lbW = hsb[buf ^ 1][1];
#pragma unroll
            for (int rt = 0; rt < 4; ++rt) {
                f32x4 s = accA[rt] + accB[rt];
                h_write(hbW, lbW, n, qg, (wrow + rt * 16 + qg * 4) >> 3,
                        fmaxf(s[0] + cur[rt].x, 0.f), fmaxf(s[1] + cur[rt].y, 0.f),
                        fmaxf(s[2] + cur[rt].z, 0.f), fmaxf(s[3] + cur[rt].w, 0.f));
            }
        }
        // out[t-1] = W_out @ h_{t-1} + b, stored directly (no exchange)
        if (douto) {
            float4 o = make_float4(oaA[0] + oaB[0] + bo4.x, oaA[1] + oaB[1] + bo4.y,
                                   oaA[2] + oaB[2] + bo4.z, oaA[3] + oaB[3] + bo4.w);
            *reinterpret_cast<float4*>(outp + (size_t)(t - 1) * O_) = o;
        }
#pragma unroll
        for (int rt = 0; rt < 4; ++rt) cur[rt] = nx[rt];
        __syncthreads();
        buf ^= 1;
    }

    // ---- epilogue: out[t_end-1] from h_{t_end-1} ----
    {
        const unsigned* hbR = hsb[buf][0];
        const unsigned* lbR = hsb[buf][1];
        f32x4 oaA = z4, oaB = z4;
#pragma unroll
        for (int kt = 0; kt < 8; ++kt) {
            const int sw = (((kt * 4 + qg) ^ (n & 7)) << 2);
            bf16x8 bhi = *reinterpret_cast<const bf16x8*>(hbR + n * 128 + sw);
            bf16x8 blo = *reinterpret_cast<const bf16x8*>(lbR + n * 128 + sw);
            oaA = MFMA16(wo_hi[kt], bhi, oaA);
            oaB = MFMA16(wo_lo[kt], bhi, oaB);
            oaB = MFMA16(wo_hi[kt], blo, oaB);
        }
        float4 o = make_float4(oaA[0] + oaB[0] + bo4.x, oaA[1] + oaB[1] + bo4.y,
                               oaA[2] + oaB[2] + bo4.z, oaA[3] + oaB[3] + bo4.w);
        *reinterpret_cast<float4*>(outp + (size_t)(t_end - 1) * O_) = o;
    }
}

// ---------------------------------------------------------------------------
extern "C" void kernel_launch(void* const* d_in, const int* in_sizes, int n_in,
                              void* d_out, int out_size, void* d_ws, size_t ws_size,
                              hipStream_t stream)
{
    (void)in_sizes; (void)n_in; (void)out_size; (void)ws_size;
    const float* x     = (const float*)d_in[0];   // [B,T,I]
    const float* W_xh  = (const float*)d_in[1];   // [H,I]
    const float* W_hh  = (const float*)d_in[2];   // [H,H]
    const float* b_h   = (const float*)d_in[3];   // [H]
    const float* W_out = (const float*)d_in[4];   // [O,H]
    const float* b_out = (const float*)d_in[5];   // [O]
    float* out = (float*)d_out;                   // [B,T,O]
    float* xw  = (float*)d_ws;                    // [T,B,H] fp32 = 128 MiB scratch

    xw_gemm_kernel<<<512, 256, 0, stream>>>(x, W_xh, b_h, xw);
    rnn_scan_kernel<<<256, 256, 0, stream>>>(xw, W_hh, W_out, b_out, out);
}

// Round 7
// 617.780 us; speedup vs baseline: 1.0721x; 1.0721x over previous
//
#include <hip/hip_runtime.h>

#define B_ 128
#define T_ 1024
#define I_ 128
#define H_ 256
#define O_ 64

// Force a float4's components to stay in VGPRs (phase A only).
#define PIN4(v) asm volatile("" : "+v"((v).x), "+v"((v).y), "+v"((v).z), "+v"((v).w))

__device__ __forceinline__ float fma4(float4 w, float4 h, float a) {
    a = fmaf(w.x, h.x, a); a = fmaf(w.y, h.y, a);
    a = fmaf(w.z, h.z, a); a = fmaf(w.w, h.w, a);
    return a;
}

// ---------------------------------------------------------------------------
// Phase A: xw[t,b,j] = sum_i x[b,t,i]*W_xh[j,i] + b_h[j]   (UNCHANGED)
// Stores [T,B,H]-transposed so the scan reads contiguous blocks per t.
// ---------------------------------------------------------------------------
__global__ __launch_bounds__(256, 2)
void xw_gemm_kernel(const float* __restrict__ x, const float* __restrict__ W_xh,
                    const float* __restrict__ b_h, float* __restrict__ xw)
{
    const int tid = threadIdx.x;
    const int jb  = tid & 31;
    const int kb  = tid >> 5;                       // 0..7
    __shared__ __align__(16) float xs[2][8 * I_];   // 2 x 4 KB
    __shared__ __align__(16) float part[64 * 264];  // 66 KB, 8 rows x 8 kg

    float4 w[8][4];                                 // W_xh[jb*8+a][kb*16+c]
#pragma unroll
    for (int a = 0; a < 8; ++a) {
        const float* wr = W_xh + (size_t)(jb * 8 + a) * I_ + kb * 16;
#pragma unroll
        for (int c4 = 0; c4 < 4; ++c4) {
            w[a][c4] = reinterpret_cast<const float4*>(wr)[c4];
            PIN4(w[a][c4]);
        }
    }
    const float bh = b_h[tid];

    const int base = blockIdx.x * 256;              // 256 rows of [B*T] per WG
    const int bidx = base >> 10;                    // batch row (T_=1024)
    const int tbas = base & 1023;                   // t offset base
    {
        const float4* xp = reinterpret_cast<const float4*>(x + (size_t)base * I_);
        reinterpret_cast<float4*>(xs[0])[tid] = xp[tid];
    }
    __syncthreads();

    int buf = 0;
    for (int tile = 0; tile < 32; ++tile) {
        float4 pre = make_float4(0.f, 0.f, 0.f, 0.f);
        if (tile + 1 < 32) {
            const float4* xp = reinterpret_cast<const float4*>(
                x + (size_t)(base + (tile + 1) * 8) * I_);
            pre = xp[tid];
        }

        float4* p4 = reinterpret_cast<float4*>(part);
#pragma unroll 1
        for (int r = 0; r < 8; ++r) {
            const float4* xr = reinterpret_cast<const float4*>(
                xs[buf] + r * I_ + kb * 16);        // broadcast reads
            float acc[8];
#pragma unroll
            for (int a = 0; a < 8; ++a) acc[a] = 0.f;
#pragma unroll
            for (int c4 = 0; c4 < 4; ++c4) {
                const float4 xv = xr[c4];
#pragma unroll
                for (int a = 0; a < 8; ++a) acc[a] = fma4(w[a][c4], xv, acc[a]);
            }
            const int rowb = (kb * 8 + r) * 66;
            p4[rowb + ((jb * 2 + 0) ^ kb)] = make_float4(acc[0], acc[1], acc[2], acc[3]);
            p4[rowb + ((jb * 2 + 1) ^ kb)] = make_float4(acc[4], acc[5], acc[6], acc[7]);
        }
        __syncthreads();

        {   // phase2: lane j=tid reduces 8 rows x 8 groups; store [T,B,H]
            const int q = tid >> 2, m = tid & 3;
            float* orow = xw + ((size_t)(tbas + tile * 8) * B_ + bidx) * H_ + tid;
#pragma unroll
            for (int r = 0; r < 8; ++r) {
                float s = 0.f;
#pragma unroll
                for (int g = 0; g < 8; ++g)
                    s += part[(g * 8 + r) * 264 + (((q ^ g) << 2) | m)];
                orow[(size_t)r * B_ * H_] = s + bh;
            }
        }
        if (tile + 1 < 32)
            reinterpret_cast<float4*>(xs[buf ^ 1])[tid] = pre;
        __syncthreads();
        buf ^= 1;
    }
}

// ---------------------------------------------------------------------------
// Phase B: MFMA scan v3. Round-6 post-mortem: register demand ~520 > 512
// (wa 256 + wo 64 + working ~200) -> scratch spills (WRITE_SIZE 78 MB vs
// 32 MB of out), AND 940 MB of xw warmup re-reads. Fixes:
//  - TWO loops: warmup loop has NO out-projection and wo frags are built only
//    at the start of the 64-step output window -> loop-live demand 256 AGPR +
//    ~110 VGPR (warmup) / +64 (output) = comfortably <= 512. No douto branch.
//  - C=16 chunks x 64-step windows: one 192-step warmup per 64 outputs ->
//    xw traffic 940 -> 512 MB.
//  - rowgroup = 8 batch rows (cols 8..15 of the MFMA N=16 zero-padded; they
//    stay exactly 0 through relu) -> 16 rowgroups x 16 chunks = 256 WGs, all
//    CUs busy, per-CU xw stream halves to 8 KB/step.
// Unchanged: split-bf16 3-term math, h hi/lo planes in 32 KB swizzled LDS,
// one barrier per step, A-frags AGPR-native.
// ---------------------------------------------------------------------------
typedef short bf16x8 __attribute__((ext_vector_type(8)));
typedef float f32x4  __attribute__((ext_vector_type(4)));
#define MFMA16(A, Bv, Cv) __builtin_amdgcn_mfma_f32_16x16x32_bf16(A, Bv, Cv, 0, 0, 0)

__device__ __forceinline__ unsigned f2bf_bits(float f) {   // RNE f32->bf16 bits
    unsigned u = __float_as_uint(f);
    return (u + 0x7FFFu + ((u >> 16) & 1u)) >> 16;
}

// Pack 4 fp32 (consecutive k) into bf16 hi+lo planes and store (swizzled).
__device__ __forceinline__ void h_write(unsigned* hibase, unsigned* lobase,
                                        int n, int qg, int s,
                                        float v0, float v1, float v2, float v3)
{
    unsigned phA, phB, plA, plB;
    asm("v_cvt_pk_bf16_f32 %0, %1, %2" : "=v"(phA) : "v"(v0), "v"(v1));
    asm("v_cvt_pk_bf16_f32 %0, %1, %2" : "=v"(phB) : "v"(v2), "v"(v3));
    float r0 = v0 - __uint_as_float(phA << 16);
    float r1 = v1 - __uint_as_float(phA & 0xFFFF0000u);
    float r2 = v2 - __uint_as_float(phB << 16);
    float r3 = v3 - __uint_as_float(phB & 0xFFFF0000u);
    asm("v_cvt_pk_bf16_f32 %0, %1, %2" : "=v"(plA) : "v"(r0), "v"(r1));
    asm("v_cvt_pk_bf16_f32 %0, %1, %2" : "=v"(plB) : "v"(r2), "v"(r3));
    const int idx = n * 128 + ((s ^ (n & 7)) << 2) + (qg & 1) * 2;
    *reinterpret_cast<uint2*>(hibase + idx) = make_uint2(phA, phB);
    *reinterpret_cast<uint2*>(lobase + idx) = make_uint2(plA, plB);
}

__global__ __launch_bounds__(256, 1)
void rnn_scan_kernel(const float* __restrict__ xw, const float* __restrict__ W_hh,
                     const float* __restrict__ W_out, const float* __restrict__ b_out,
                     float* __restrict__ out)
{
    const int tid  = threadIdx.x;
    const int n    = tid & 15;            // batch col within WG (8 real + 8 pad)
    const int qg   = (tid >> 4) & 3;      // quad group within wave
    const int w    = tid >> 6;            // wave 0..3
    const int wrow = w * 64;              // h-output row base (4 row-tiles)

    const int rg = blockIdx.x & 15;       // row group (8 batch rows)
    const int c  = blockIdx.x >> 4;       // time chunk 0..15
    const int r0 = rg * 8;
    const bool valid = (n < 8);

    const int out_lo = c * 64;            // output window [out_lo, out_lo+64)
    const int t_end  = out_lo + 64;
    const int t0     = (out_lo > 192) ? (out_lo - 192) : 0;   // c<=3 exact

    __shared__ unsigned hsb[2][2][2048];  // [buf][hi/lo][16 cols x 128 uint] 32 KB

    // ---- W_hh A-fragments (split bf16 hi+lo), AGPR-resident ----
    bf16x8 wa_hi[4][8], wa_lo[4][8];
#pragma unroll
    for (int rt = 0; rt < 4; ++rt)
#pragma unroll
        for (int kt = 0; kt < 8; ++kt) {
            const float* wp = W_hh + (size_t)(wrow + rt * 16 + n) * H_ + kt * 32 + qg * 8;
            bf16x8 hi8, lo8;
#pragma unroll
            for (int j = 0; j < 8; ++j) {
                float f = wp[j];
                unsigned hb = f2bf_bits(f);
                hi8[j] = (short)hb;
                lo8[j] = (short)f2bf_bits(f - __uint_as_float(hb << 16));
            }
            wa_hi[rt][kt] = hi8; wa_lo[rt][kt] = lo8;
        }

    const float4 bo4 = *reinterpret_cast<const float4*>(b_out + w * 16 + qg * 4);
    float* outp = out + ((size_t)(r0 + (valid ? n : 0)) * T_) * O_ + w * 16 + qg * 4;

    // ---- prologue: h_{t0} = relu(xw[t0]) into buf 0; prime xw[t0+1] ----
    {
        const float* xp = xw + ((size_t)t0 * B_ + (r0 + n)) * H_;
#pragma unroll
        for (int rt = 0; rt < 4; ++rt) {
            float4 a = make_float4(0.f, 0.f, 0.f, 0.f);
            if (valid) a = *reinterpret_cast<const float4*>(xp + wrow + rt * 16 + qg * 4);
            h_write(hsb[0][0], hsb[0][1], n, qg, (wrow + rt * 16 + qg * 4) >> 3,
                    fmaxf(a.x, 0.f), fmaxf(a.y, 0.f), fmaxf(a.z, 0.f), fmaxf(a.w, 0.f));
        }
    }
    float4 cur[4];
    {
        const float* xp = xw + ((size_t)(t0 + 1) * B_ + (r0 + n)) * H_;
#pragma unroll
        for (int rt = 0; rt < 4; ++rt) {
            cur[rt] = make_float4(0.f, 0.f, 0.f, 0.f);
            if (valid) cur[rt] = *reinterpret_cast<const float4*>(xp + wrow + rt * 16 + qg * 4);
        }
    }
    __syncthreads();

    int buf = 0;
    const f32x4 z4 = {0.f, 0.f, 0.f, 0.f};

    // ================= warmup loop: t in (t0, out_lo], no out-proj =========
#pragma unroll 1
    for (int t = t0 + 1; t <= out_lo; ++t) {
        const float* xp = xw + ((size_t)(t + 1) * B_ + (r0 + n)) * H_;  // t+1 <= out_lo+1 < T_
        float4 nx[4];
#pragma unroll
        for (int rt = 0; rt < 4; ++rt) {
            nx[rt] = make_float4(0.f, 0.f, 0.f, 0.f);
            if (valid) nx[rt] = *reinterpret_cast<const float4*>(xp + wrow + rt * 16 + qg * 4);
        }

        const unsigned* hbR = hsb[buf][0];
        const unsigned* lbR = hsb[buf][1];
        f32x4 accA[4], accB[4];
#pragma unroll
        for (int rt = 0; rt < 4; ++rt) { accA[rt] = z4; accB[rt] = z4; }

#pragma unroll
        for (int kt = 0; kt < 8; ++kt) {
            const int sw = (((kt * 4 + qg) ^ (n & 7)) << 2);
            bf16x8 bhi = *reinterpret_cast<const bf16x8*>(hbR + n * 128 + sw);
            bf16x8 blo = *reinterpret_cast<const bf16x8*>(lbR + n * 128 + sw);
#pragma unroll
            for (int rt = 0; rt < 4; ++rt) {
                accA[rt] = MFMA16(wa_hi[rt][kt], bhi, accA[rt]);
                accB[rt] = MFMA16(wa_lo[rt][kt], bhi, accB[rt]);
                accB[rt] = MFMA16(wa_hi[rt][kt], blo, accB[rt]);
            }
        }

        unsigned* hbW = hsb[buf ^ 1][0];
        unsigned* lbW = hsb[buf ^ 1][1];
#pragma unroll
        for (int rt = 0; rt < 4; ++rt) {
            f32x4 s = accA[rt] + accB[rt];
            h_write(hbW, lbW, n, qg, (wrow + rt * 16 + qg * 4) >> 3,
                    fmaxf(s[0] + cur[rt].x, 0.f), fmaxf(s[1] + cur[rt].y, 0.f),
                    fmaxf(s[2] + cur[rt].z, 0.f), fmaxf(s[3] + cur[rt].w, 0.f));
        }
#pragma unroll
        for (int rt = 0; rt < 4; ++rt) cur[rt] = nx[rt];
        __syncthreads();
        buf ^= 1;
    }

    // ---- build W_out fragments only now (output window) ----
    bf16x8 wo_hi[8], wo_lo[8];
#pragma unroll
    for (int kt = 0; kt < 8; ++kt) {
        const float* op = W_out + (size_t)(w * 16 + n) * H_ + kt * 32 + qg * 8;
        bf16x8 hi8, lo8;
#pragma unroll
        for (int j = 0; j < 8; ++j) {
            float f = op[j];
            unsigned hb = f2bf_bits(f);
            hi8[j] = (short)hb;
            lo8[j] = (short)f2bf_bits(f - __uint_as_float(hb << 16));
        }
        wo_hi[kt] = hi8; wo_lo[kt] = lo8;
    }

    // ================= output loop: t in (out_lo, t_end) ===================
#pragma unroll 1
    for (int t = out_lo + 1; t < t_end; ++t) {
        const int tt = (t + 1 < T_) ? (t + 1) : (T_ - 1);
        const float* xp = xw + ((size_t)tt * B_ + (r0 + n)) * H_;
        float4 nx[4];
#pragma unroll
        for (int rt = 0; rt < 4; ++rt) {
            nx[rt] = make_float4(0.f, 0.f, 0.f, 0.f);
            if (valid) nx[rt] = *reinterpret_cast<const float4*>(xp + wrow + rt * 16 + qg * 4);
        }

        const unsigned* hbR = hsb[buf][0];
        const unsigned* lbR = hsb[buf][1];
        f32x4 accA[4], accB[4];
#pragma unroll
        for (int rt = 0; rt < 4; ++rt) { accA[rt] = z4; accB[rt] = z4; }
        f32x4 oaA = z4, oaB = z4;

#pragma unroll
        for (int kt = 0; kt < 8; ++kt) {
            const int sw = (((kt * 4 + qg) ^ (n & 7)) << 2);
            bf16x8 bhi = *reinterpret_cast<const bf16x8*>(hbR + n * 128 + sw);
            bf16x8 blo = *reinterpret_cast<const bf16x8*>(lbR + n * 128 + sw);
#pragma unroll
            for (int rt = 0; rt < 4; ++rt) {
                accA[rt] = MFMA16(wa_hi[rt][kt], bhi, accA[rt]);
                accB[rt] = MFMA16(wa_lo[rt][kt], bhi, accB[rt]);
                accB[rt] = MFMA16(wa_hi[rt][kt], blo, accB[rt]);
            }
            oaA = MFMA16(wo_hi[kt], bhi, oaA);
            oaB = MFMA16(wo_lo[kt], bhi, oaB);
            oaB = MFMA16(wo_hi[kt], blo, oaB);
        }

        unsigned* hbW = hsb[buf ^ 1][0];
        unsigned* lbW = hsb[buf ^ 1][1];
#pragma unroll
        for (int rt = 0; rt < 4; ++rt) {
            f32x4 s = accA[rt] + accB[rt];
            h_write(hbW, lbW, n, qg, (wrow + rt * 16 + qg * 4) >> 3,
                    fmaxf(s[0] + cur[rt].x, 0.f), fmaxf(s[1] + cur[rt].y, 0.f),
                    fmaxf(s[2] + cur[rt].z, 0.f), fmaxf(s[3] + cur[rt].w, 0.f));
        }
        if (valid) {
            float4 o = make_float4(oaA[0] + oaB[0] + bo4.x, oaA[1] + oaB[1] + bo4.y,
                                   oaA[2] + oaB[2] + bo4.z, oaA[3] + oaB[3] + bo4.w);
            *reinterpret_cast<float4*>(outp + (size_t)(t - 1) * O_) = o;
        }
#pragma unroll
        for (int rt = 0; rt < 4; ++rt) cur[rt] = nx[rt];
        __syncthreads();
        buf ^= 1;
    }

    // ---- epilogue: out[t_end-1] from h_{t_end-1} ----
    {
        const unsigned* hbR = hsb[buf][0];
        const unsigned* lbR = hsb[buf][1];
        f32x4 oaA = z4, oaB = z4;
#pragma unroll
        for (int kt = 0; kt < 8; ++kt) {
            const int sw = (((kt * 4 + qg) ^ (n & 7)) << 2);
            bf16x8 bhi = *reinterpret_cast<const bf16x8*>(hbR + n * 128 + sw);
            bf16x8 blo = *reinterpret_cast<const bf16x8*>(lbR + n * 128 + sw);
            oaA = MFMA16(wo_hi[kt], bhi, oaA);
            oaB = MFMA16(wo_lo[kt], bhi, oaB);
            oaB = MFMA16(wo_hi[kt], blo, oaB);
        }
        if (valid) {
            float4 o = make_float4(oaA[0] + oaB[0] + bo4.x, oaA[1] + oaB[1] + bo4.y,
                                   oaA[2] + oaB[2] + bo4.z, oaA[3] + oaB[3] + bo4.w);
            *reinterpret_cast<float4*>(outp + (size_t)(t_end - 1) * O_) = o;
        }
    }
}

// ---------------------------------------------------------------------------
extern "C" void kernel_launch(void* const* d_in, const int* in_sizes, int n_in,
                              void* d_out, int out_size, void* d_ws, size_t ws_size,
                              hipStream_t stream)
{
    (void)in_sizes; (void)n_in; (void)out_size; (void)ws_size;
    const float* x     = (const float*)d_in[0];   // [B,T,I]
    const float* W_xh  = (const float*)d_in[1];   // [H,I]
    const float* W_hh  = (const float*)d_in[2];   // [H,H]
    const float* b_h   = (const float*)d_in[3];   // [H]
    const float* W_out = (const float*)d_in[4];   // [O,H]
    const float* b_out = (const float*)d_in[5];   // [O]
    float* out = (float*)d_out;                   // [B,T,O]
    float* xw  = (float*)d_ws;                    // [T,B,H] fp32 = 128 MiB scratch

    xw_gemm_kernel<<<512, 256, 0, stream>>>(x, W_xh, b_h, xw);
    rnn_scan_kernel<<<256, 256, 0, stream>>>(xw, W_hh, W_out, b_out, out);
}

// Round 8
// 524.827 us; speedup vs baseline: 1.2620x; 1.1771x over previous
//
#include <hip/hip_runtime.h>

#define B_ 128
#define T_ 1024
#define I_ 128
#define H_ 256
#define O_ 64

// Force a float4's components to stay in VGPRs (phase A only).
#define PIN4(v) asm volatile("" : "+v"((v).x), "+v"((v).y), "+v"((v).z), "+v"((v).w))

__device__ __forceinline__ float fma4(float4 w, float4 h, float a) {
    a = fmaf(w.x, h.x, a); a = fmaf(w.y, h.y, a);
    a = fmaf(w.z, h.z, a); a = fmaf(w.w, h.w, a);
    return a;
}

// ---------------------------------------------------------------------------
// Phase A: xw[t,b,j] = sum_i x[b,t,i]*W_xh[j,i] + b_h[j]   (UNCHANGED)
// Stores [T,B,H]-transposed so the scan reads contiguous blocks per t.
// ---------------------------------------------------------------------------
__global__ __launch_bounds__(256, 2)
void xw_gemm_kernel(const float* __restrict__ x, const float* __restrict__ W_xh,
                    const float* __restrict__ b_h, float* __restrict__ xw)
{
    const int tid = threadIdx.x;
    const int jb  = tid & 31;
    const int kb  = tid >> 5;                       // 0..7
    __shared__ __align__(16) float xs[2][8 * I_];   // 2 x 4 KB
    __shared__ __align__(16) float part[64 * 264];  // 66 KB, 8 rows x 8 kg

    float4 w[8][4];                                 // W_xh[jb*8+a][kb*16+c]
#pragma unroll
    for (int a = 0; a < 8; ++a) {
        const float* wr = W_xh + (size_t)(jb * 8 + a) * I_ + kb * 16;
#pragma unroll
        for (int c4 = 0; c4 < 4; ++c4) {
            w[a][c4] = reinterpret_cast<const float4*>(wr)[c4];
            PIN4(w[a][c4]);
        }
    }
    const float bh = b_h[tid];

    const int base = blockIdx.x * 256;              // 256 rows of [B*T] per WG
    const int bidx = base >> 10;                    // batch row (T_=1024)
    const int tbas = base & 1023;                   // t offset base
    {
        const float4* xp = reinterpret_cast<const float4*>(x + (size_t)base * I_);
        reinterpret_cast<float4*>(xs[0])[tid] = xp[tid];
    }
    __syncthreads();

    int buf = 0;
    for (int tile = 0; tile < 32; ++tile) {
        float4 pre = make_float4(0.f, 0.f, 0.f, 0.f);
        if (tile + 1 < 32) {
            const float4* xp = reinterpret_cast<const float4*>(
                x + (size_t)(base + (tile + 1) * 8) * I_);
            pre = xp[tid];
        }

        float4* p4 = reinterpret_cast<float4*>(part);
#pragma unroll 1
        for (int r = 0; r < 8; ++r) {
            const float4* xr = reinterpret_cast<const float4*>(
                xs[buf] + r * I_ + kb * 16);        // broadcast reads
            float acc[8];
#pragma unroll
            for (int a = 0; a < 8; ++a) acc[a] = 0.f;
#pragma unroll
            for (int c4 = 0; c4 < 4; ++c4) {
                const float4 xv = xr[c4];
#pragma unroll
                for (int a = 0; a < 8; ++a) acc[a] = fma4(w[a][c4], xv, acc[a]);
            }
            const int rowb = (kb * 8 + r) * 66;
            p4[rowb + ((jb * 2 + 0) ^ kb)] = make_float4(acc[0], acc[1], acc[2], acc[3]);
            p4[rowb + ((jb * 2 + 1) ^ kb)] = make_float4(acc[4], acc[5], acc[6], acc[7]);
        }
        __syncthreads();

        {   // phase2: lane j=tid reduces 8 rows x 8 groups; store [T,B,H]
            const int q = tid >> 2, m = tid & 3;
            float* orow = xw + ((size_t)(tbas + tile * 8) * B_ + bidx) * H_ + tid;
#pragma unroll
            for (int r = 0; r < 8; ++r) {
                float s = 0.f;
#pragma unroll
                for (int g = 0; g < 8; ++g)
                    s += part[(g * 8 + r) * 264 + (((q ^ g) << 2) | m)];
                orow[(size_t)r * B_ * H_] = s + bh;
            }
        }
        if (tile + 1 < 32)
            reinterpret_cast<float4*>(xs[buf ^ 1])[tid] = pre;
        __syncthreads();
        buf ^= 1;
    }
}

// ---------------------------------------------------------------------------
// Phase B: MFMA scan v4 — 8 waves, 2 waves/SIMD.
// Round-7 post-mortem: registers clean but 256-thr/1-WG/CU = 1 wave/SIMD ->
// zero latency hiding, step 4160 cyc vs ~1200 sum-of-floors. Fix: 512 thr,
// wave w owns 2 row-tiles [w*32,+32) -> wa = 128 regs; at
// __launch_bounds__(512,2) the 256-reg tier holds 2 waves/SIMD.
// Out-projection: k-half split (waves 0-3 kt 0..3, waves 4-7 kt 4..7) with
// 1-step-lag opart exchange (round-5 proven), built & used ONLY in the
// 64-step output window (warmup live set ~210 regs, output ~250).
// Unchanged: split-bf16 3-term math, hi/lo h-planes in swizzled LDS,
// one barrier/step, [T,B,H] xw, 16 rowgroups (8 cols, N-pad) x 16 chunks,
// warmup 192.
// ---------------------------------------------------------------------------
typedef short bf16x8 __attribute__((ext_vector_type(8)));
typedef float f32x4  __attribute__((ext_vector_type(4)));
#define MFMA16(A, Bv, Cv) __builtin_amdgcn_mfma_f32_16x16x32_bf16(A, Bv, Cv, 0, 0, 0)

__device__ __forceinline__ unsigned f2bf_bits(float f) {   // RNE f32->bf16 bits
    unsigned u = __float_as_uint(f);
    return (u + 0x7FFFu + ((u >> 16) & 1u)) >> 16;
}

// Pack 4 fp32 (consecutive k) into bf16 hi+lo planes and store (swizzled).
__device__ __forceinline__ void h_write(unsigned* hibase, unsigned* lobase,
                                        int n, int qg, int s,
                                        float v0, float v1, float v2, float v3)
{
    unsigned phA, phB, plA, plB;
    asm("v_cvt_pk_bf16_f32 %0, %1, %2" : "=v"(phA) : "v"(v0), "v"(v1));
    asm("v_cvt_pk_bf16_f32 %0, %1, %2" : "=v"(phB) : "v"(v2), "v"(v3));
    float r0 = v0 - __uint_as_float(phA << 16);
    float r1 = v1 - __uint_as_float(phA & 0xFFFF0000u);
    float r2 = v2 - __uint_as_float(phB << 16);
    float r3 = v3 - __uint_as_float(phB & 0xFFFF0000u);
    asm("v_cvt_pk_bf16_f32 %0, %1, %2" : "=v"(plA) : "v"(r0), "v"(r1));
    asm("v_cvt_pk_bf16_f32 %0, %1, %2" : "=v"(plB) : "v"(r2), "v"(r3));
    const int idx = n * 128 + ((s ^ (n & 7)) << 2) + (qg & 1) * 2;
    *reinterpret_cast<uint2*>(hibase + idx) = make_uint2(phA, phB);
    *reinterpret_cast<uint2*>(lobase + idx) = make_uint2(plA, plB);
}

__global__ __launch_bounds__(512, 2)
void rnn_scan_kernel(const float* __restrict__ xw, const float* __restrict__ W_hh,
                     const float* __restrict__ W_out, const float* __restrict__ b_out,
                     float* __restrict__ out)
{
    const int tid  = threadIdx.x;
    const int n    = tid & 15;            // batch col within WG (8 real + 8 pad)
    const int qg   = (tid >> 4) & 3;      // quad group within wave
    const int w    = tid >> 6;            // wave 0..7
    const int wrow = w * 32;              // h-output row base (2 row-tiles)

    const int rg = blockIdx.x & 15;       // row group (8 batch rows)
    const int c  = blockIdx.x >> 4;       // time chunk 0..15
    const int r0 = rg * 8;
    const bool valid = (n < 8);

    const int out_lo = c * 64;            // output window [out_lo, out_lo+64)
    const int t_end  = out_lo + 64;
    const int t0     = (out_lo > 192) ? (out_lo - 192) : 0;   // c<=3 exact

    __shared__ unsigned hsb[2][2][2048];  // [buf][hi/lo][16 cols x 128 uint] 32 KB
    __shared__ float4 opart[2][256];      // out-proj k-half partials, 8 KB

    // ---- W_hh A-fragments (split bf16 hi+lo), AGPR-resident: 128 regs ----
    bf16x8 wa_hi[2][8], wa_lo[2][8];
#pragma unroll
    for (int rt = 0; rt < 2; ++rt)
#pragma unroll
        for (int kt = 0; kt < 8; ++kt) {
            const float* wp = W_hh + (size_t)(wrow + rt * 16 + n) * H_ + kt * 32 + qg * 8;
            bf16x8 hi8, lo8;
#pragma unroll
            for (int j = 0; j < 8; ++j) {
                float f = wp[j];
                unsigned hb = f2bf_bits(f);
                hi8[j] = (short)hb;
                lo8[j] = (short)f2bf_bits(f - __uint_as_float(hb << 16));
            }
            wa_hi[rt][kt] = hi8; wa_lo[rt][kt] = lo8;
        }

    const float4 bo4 = *reinterpret_cast<const float4*>(b_out + (w & 3) * 16 + qg * 4);
    float* outp = out + ((size_t)(r0 + (valid ? n : 0)) * T_) * O_ + (w & 3) * 16 + qg * 4;

    // ---- prologue: h_{t0} = relu(xw[t0]) into buf 0; prime xw[t0+1] ----
    {
        const float* xp = xw + ((size_t)t0 * B_ + (r0 + n)) * H_;
#pragma unroll
        for (int rt = 0; rt < 2; ++rt) {
            float4 a = make_float4(0.f, 0.f, 0.f, 0.f);
            if (valid) a = *reinterpret_cast<const float4*>(xp + wrow + rt * 16 + qg * 4);
            h_write(hsb[0][0], hsb[0][1], n, qg, (wrow + rt * 16 + qg * 4) >> 3,
                    fmaxf(a.x, 0.f), fmaxf(a.y, 0.f), fmaxf(a.z, 0.f), fmaxf(a.w, 0.f));
        }
    }
    float4 cur[2];
    {
        const float* xp = xw + ((size_t)(t0 + 1) * B_ + (r0 + n)) * H_;
#pragma unroll
        for (int rt = 0; rt < 2; ++rt) {
            cur[rt] = make_float4(0.f, 0.f, 0.f, 0.f);
            if (valid) cur[rt] = *reinterpret_cast<const float4*>(xp + wrow + rt * 16 + qg * 4);
        }
    }
    __syncthreads();

    int buf = 0;
    const f32x4 z4 = {0.f, 0.f, 0.f, 0.f};

    // ================= warmup loop: t in (t0, out_lo], no out-proj =========
#pragma unroll 1
    for (int t = t0 + 1; t <= out_lo; ++t) {
        const float* xp = xw + ((size_t)(t + 1) * B_ + (r0 + n)) * H_;
        float4 nx[2];
#pragma unroll
        for (int rt = 0; rt < 2; ++rt) {
            nx[rt] = make_float4(0.f, 0.f, 0.f, 0.f);
            if (valid) nx[rt] = *reinterpret_cast<const float4*>(xp + wrow + rt * 16 + qg * 4);
        }

        const unsigned* hbR = hsb[buf][0];
        const unsigned* lbR = hsb[buf][1];
        f32x4 accA[2], accB[2];
#pragma unroll
        for (int rt = 0; rt < 2; ++rt) { accA[rt] = z4; accB[rt] = z4; }

#pragma unroll
        for (int kt = 0; kt < 8; ++kt) {
            const int sw = (((kt * 4 + qg) ^ (n & 7)) << 2);
            bf16x8 bhi = *reinterpret_cast<const bf16x8*>(hbR + n * 128 + sw);
            bf16x8 blo = *reinterpret_cast<const bf16x8*>(lbR + n * 128 + sw);
#pragma unroll
            for (int rt = 0; rt < 2; ++rt) {
                accA[rt] = MFMA16(wa_hi[rt][kt], bhi, accA[rt]);
                accB[rt] = MFMA16(wa_lo[rt][kt], bhi, accB[rt]);
                accB[rt] = MFMA16(wa_hi[rt][kt], blo, accB[rt]);
            }
        }

        unsigned* hbW = hsb[buf ^ 1][0];
        unsigned* lbW = hsb[buf ^ 1][1];
#pragma unroll
        for (int rt = 0; rt < 2; ++rt) {
            f32x4 s = accA[rt] + accB[rt];
            h_write(hbW, lbW, n, qg, (wrow + rt * 16 + qg * 4) >> 3,
                    fmaxf(s[0] + cur[rt].x, 0.f), fmaxf(s[1] + cur[rt].y, 0.f),
                    fmaxf(s[2] + cur[rt].z, 0.f), fmaxf(s[3] + cur[rt].w, 0.f));
        }
#pragma unroll
        for (int rt = 0; rt < 2; ++rt) cur[rt] = nx[rt];
        __syncthreads();
        buf ^= 1;
    }

    // ---- build W_out k-half fragments only now (output window) ----
    // waves 0..3: kt 0..3; waves 4..7: kt 4..7; out-rows (w&3)*16..+16
    bf16x8 wo_hi[4], wo_lo[4];
    const int khb = (w >> 2) * 4;
#pragma unroll
    for (int kk = 0; kk < 4; ++kk) {
        const float* op = W_out + (size_t)((w & 3) * 16 + n) * H_ + (khb + kk) * 32 + qg * 8;
        bf16x8 hi8, lo8;
#pragma unroll
        for (int j = 0; j < 8; ++j) {
            float f = op[j];
            unsigned hb = f2bf_bits(f);
            hi8[j] = (short)hb;
            lo8[j] = (short)f2bf_bits(f - __uint_as_float(hb << 16));
        }
        wo_hi[kk] = hi8; wo_lo[kk] = lo8;
    }

    f32x4 osave = z4;

    // ================= output loop: t in (out_lo, t_end) ===================
#pragma unroll 1
    for (int t = out_lo + 1; t < t_end; ++t) {
        const int tt = (t + 1 < T_) ? (t + 1) : (T_ - 1);
        const float* xp = xw + ((size_t)tt * B_ + (r0 + n)) * H_;
        float4 nx[2];
#pragma unroll
        for (int rt = 0; rt < 2; ++rt) {
            nx[rt] = make_float4(0.f, 0.f, 0.f, 0.f);
            if (valid) nx[rt] = *reinterpret_cast<const float4*>(xp + wrow + rt * 16 + qg * 4);
        }

        // finish out[t-2]: partner's k-half partial written last step
        if (w < 4 && t - 2 >= out_lo && valid) {
            float4 pp = opart[buf ^ 1][w * 64 + qg * 16 + n];
            float4 o = make_float4(osave[0] + pp.x + bo4.x, osave[1] + pp.y + bo4.y,
                                   osave[2] + pp.z + bo4.z, osave[3] + pp.w + bo4.w);
            *reinterpret_cast<float4*>(outp + (size_t)(t - 2) * O_) = o;
        }

        const unsigned* hbR = hsb[buf][0];
        const unsigned* lbR = hsb[buf][1];
        f32x4 accA[2], accB[2];
#pragma unroll
        for (int rt = 0; rt < 2; ++rt) { accA[rt] = z4; accB[rt] = z4; }
        f32x4 oaA = z4, oaB = z4;

#pragma unroll
        for (int kt = 0; kt < 8; ++kt) {
            const int sw = (((kt * 4 + qg) ^ (n & 7)) << 2);
            bf16x8 bhi = *reinterpret_cast<const bf16x8*>(hbR + n * 128 + sw);
            bf16x8 blo = *reinterpret_cast<const bf16x8*>(lbR + n * 128 + sw);
#pragma unroll
            for (int rt = 0; rt < 2; ++rt) {
                accA[rt] = MFMA16(wa_hi[rt][kt], bhi, accA[rt]);
                accB[rt] = MFMA16(wa_lo[rt][kt], bhi, accB[rt]);
                accB[rt] = MFMA16(wa_hi[rt][kt], blo, accB[rt]);
            }
            if ((kt >> 2) == (w >> 2)) {          // this wave's k-half
                const int kk = kt & 3;
                oaA = MFMA16(wo_hi[kk], bhi, oaA);
                oaB = MFMA16(wo_lo[kk], bhi, oaB);
                oaB = MFMA16(wo_hi[kk], blo, oaB);
            }
        }

        unsigned* hbW = hsb[buf ^ 1][0];
        unsigned* lbW = hsb[buf ^ 1][1];
#pragma unroll
        for (int rt = 0; rt < 2; ++rt) {
            f32x4 s = accA[rt] + accB[rt];
            h_write(hbW, lbW, n, qg, (wrow + rt * 16 + qg * 4) >> 3,
                    fmaxf(s[0] + cur[rt].x, 0.f), fmaxf(s[1] + cur[rt].y, 0.f),
                    fmaxf(s[2] + cur[rt].z, 0.f), fmaxf(s[3] + cur[rt].w, 0.f));
        }
        {   // out-proj partial hand-off (1-step lag, double-buffered)
            f32x4 oa = oaA + oaB;
            if (w >= 4)
                opart[buf][(w - 4) * 64 + qg * 16 + n] = make_float4(oa[0], oa[1], oa[2], oa[3]);
            else
                osave = oa;
        }
#pragma unroll
        for (int rt = 0; rt < 2; ++rt) cur[rt] = nx[rt];
        __syncthreads();
        buf ^= 1;
    }

    // ---- drain: out[t_end-2] then out[t_end-1] ----
    if (w < 4 && valid) {
        float4 pp = opart[buf ^ 1][w * 64 + qg * 16 + n];
        float4 o = make_float4(osave[0] + pp.x + bo4.x, osave[1] + pp.y + bo4.y,
                               osave[2] + pp.z + bo4.z, osave[3] + pp.w + bo4.w);
        *reinterpret_cast<float4*>(outp + (size_t)(t_end - 2) * O_) = o;
    }
    {
        const unsigned* hbR = hsb[buf][0];
        const unsigned* lbR = hsb[buf][1];
        f32x4 oaA = z4, oaB = z4;
#pragma unroll
        for (int kk = 0; kk < 4; ++kk) {
            const int kt = khb + kk;
            const int sw = (((kt * 4 + qg) ^ (n & 7)) << 2);
            bf16x8 bhi = *reinterpret_cast<const bf16x8*>(hbR + n * 128 + sw);
            bf16x8 blo = *reinterpret_cast<const bf16x8*>(lbR + n * 128 + sw);
            oaA = MFMA16(wo_hi[kk], bhi, oaA);
            oaB = MFMA16(wo_lo[kk], bhi, oaB);
            oaB = MFMA16(wo_hi[kk], blo, oaB);
        }
        f32x4 oa = oaA + oaB;
        if (w >= 4)
            opart[buf][(w - 4) * 64 + qg * 16 + n] = make_float4(oa[0], oa[1], oa[2], oa[3]);
        __syncthreads();
        if (w < 4 && valid) {
            float4 pp = opart[buf][w * 64 + qg * 16 + n];
            float4 o = make_float4(oa[0] + pp.x + bo4.x, oa[1] + pp.y + bo4.y,
                                   oa[2] + pp.z + bo4.z, oa[3] + pp.w + bo4.w);
            *reinterpret_cast<float4*>(outp + (size_t)(t_end - 1) * O_) = o;
        }
    }
}

// ---------------------------------------------------------------------------
extern "C" void kernel_launch(void* const* d_in, const int* in_sizes, int n_in,
                              void* d_out, int out_size, void* d_ws, size_t ws_size,
                              hipStream_t stream)
{
    (void)in_sizes; (void)n_in; (void)out_size; (void)ws_size;
    const float* x     = (const float*)d_in[0];   // [B,T,I]
    const float* W_xh  = (const float*)d_in[1];   // [H,I]
    const float* W_hh  = (const float*)d_in[2];   // [H,H]
    const float* b_h   = (const float*)d_in[3];   // [H]
    const float* W_out = (const float*)d_in[4];   // [O,H]
    const float* b_out = (const float*)d_in[5];   // [O]
    float* out = (float*)d_out;                   // [B,T,O]
    float* xw  = (float*)d_ws;                    // [T,B,H] fp32 = 128 MiB scratch

    xw_gemm_kernel<<<512, 256, 0, stream>>>(x, W_xh, b_h, xw);
    rnn_scan_kernel<<<256, 512, 0, stream>>>(xw, W_hh, W_out, b_out, out);
}